// Round 2
// baseline (169.818 us; speedup 1.0000x reference)
//
#include <hip/hip_runtime.h>
#include <hip/hip_bf16.h>

// ---------------------------------------------------------------------------
// Abbe lithography forward model.
// Math reductions: doses factor out (I(d)=d^2*I(1)); all fft/ifftshift phases
// cancel in |AA|^2; weight cancels against norm_I.
// Pipeline:
//   A : per-source weights, compaction, scalar S = 1/(512^4*1.44*sum(w*obl^2))
//   B1: row FFT of mask (sign -1), keep 241 window cols  -> R1t[beta][y]
//   B2: col FFT (sign -1), keep 241 window rows          -> W[alpha][beta]
//   C1: per source: row IDFT (sign +1) of W .* P_s       -> T2[s][x][alpha]
//   C2: per source: col IDFT (sign +1), acc += w*|AA|^2  -> acc[part][x][y]
//   D : out[0][k] = S*d_k^2*acc ; out[1][k] = sigmoid(30*(I-0.225))
// FFT-512: radix-8, 3 stages, one wave per FFT, 8 complex regs/thread,
// LDS exchange between stages. Twiddles from per-block LDS table built in
// double precision (no chained cmul error, no hw-sin error).
// Output reg u2 of lane L holds X[(L>>3) + 8*(L&7) + 64*u2].
// ---------------------------------------------------------------------------

#define SPLIT 4

static const size_t ACC_BYTES  = (size_t)SPLIT * 512 * 512 * 4;   // 4 MiB
static const size_t O_ACC      = 4096;
static const size_t O_WIN      = O_ACC + ACC_BYTES;               // 241*241 cplx
static const size_t O_R1       = O_WIN + 464896;                  // 241*512 cplx
static const size_t O_T2       = O_R1 + 987136;
static const size_t SLOT_BYTES = (size_t)512 * 244 * 8;           // 999424

__device__ inline float2 cadd(float2 a, float2 b){ return make_float2(a.x+b.x, a.y+b.y); }
__device__ inline float2 csub(float2 a, float2 b){ return make_float2(a.x-b.x, a.y-b.y); }
__device__ inline float2 cmul(float2 a, float2 b){
  return make_float2(fmaf(a.x, b.x, -(a.y*b.y)), fmaf(a.x, b.y, a.y*b.x));
}

// Build 512-entry twiddle table exp(+2*pi*i*k/512) in LDS, double-accurate.
template<int BLOCK>
__device__ inline void build_tw(float2* twtab) {
  for (int k = (int)threadIdx.x; k < 512; k += BLOCK) {
    double a = 6.283185307179586476925286766559 * (double)k / 512.0;
    twtab[k] = make_float2((float)cos(a), (float)sin(a));
  }
  __syncthreads();
}

// DFT-8 (sign S), DIF radix-2x3, outputs placed in natural order.
template<int S>
__device__ inline void dft8(float2 v[8]) {
  const float sg = (float)S;
  const float C7 = 0.7071067811865476f;
  float2 t0=cadd(v[0],v[4]), t4=csub(v[0],v[4]);
  float2 t1=cadd(v[1],v[5]), t5=csub(v[1],v[5]);
  float2 t2=cadd(v[2],v[6]), t6=csub(v[2],v[6]);
  float2 t3=cadd(v[3],v[7]), t7=csub(v[3],v[7]);
  t5 = make_float2(C7*(t5.x - sg*t5.y), C7*(t5.y + sg*t5.x));   // *W8^1
  t6 = make_float2(-sg*t6.y, sg*t6.x);                          // *W8^2
  t7 = make_float2(C7*(-t7.x - sg*t7.y), C7*(sg*t7.x - t7.y));  // *W8^3
  float2 u0=cadd(t0,t2), u2=csub(t0,t2);
  float2 u1=cadd(t1,t3), u3=csub(t1,t3);
  u3 = make_float2(-sg*u3.y, sg*u3.x);
  float2 u4=cadd(t4,t6), u6=csub(t4,t6);
  float2 u5=cadd(t5,t7), u7=csub(t5,t7);
  u7 = make_float2(-sg*u7.y, sg*u7.x);
  v[0]=cadd(u0,u1); v[4]=csub(u0,u1);
  v[2]=cadd(u2,u3); v[6]=csub(u2,u3);
  v[1]=cadd(u4,u5); v[5]=csub(u4,u5);
  v[3]=cadd(u6,u7); v[7]=csub(u6,u7);
}

__device__ inline float2 twsgn(float2 t, int S) {
  return make_float2(t.x, (S > 0) ? t.y : -t.y);
}

// One-wave FFT-512. In: v[q]=x[64q+lane]. Out: v[u2]=X[(lane>>3)+8*(lane&7)+64*u2].
// xch: per-wave float2[512] LDS buffer; twtab: 512-entry exp(+2pi i k/512).
// All waves of the block must call this the same number of times.
template<int S>
__device__ inline void wfft512(float2 v[8], int lane, float2* xch,
                               const float2* twtab) {
  dft8<S>(v);
  #pragma unroll
  for (int u = 1; u < 8; u++)
    v[u] = cmul(v[u], twsgn(twtab[(lane * u) & 511], S));
  __syncthreads();
  #pragma unroll
  for (int u = 0; u < 8; u++) xch[u*64 + lane] = v[u];
  __syncthreads();
  int u0 = lane >> 3, p2 = lane & 7;
  #pragma unroll
  for (int q = 0; q < 8; q++) v[q] = xch[u0*64 + q*8 + p2];
  dft8<S>(v);
  #pragma unroll
  for (int u = 1; u < 8; u++)
    v[u] = cmul(v[u], twsgn(twtab[(p2 * u) << 3], S));
  __syncthreads();
  #pragma unroll
  for (int u = 0; u < 8; u++) xch[u0*64 + u*8 + p2] = v[u];
  __syncthreads();
  #pragma unroll
  for (int q = 0; q < 8; q++) v[q] = xch[u0*64 + p2*8 + q];
  dft8<S>(v);
}

// --- A: weights, compaction, scalar ----------------------------------------
__global__ void __launch_bounds__(256) k_setup(const float* prm, const float* sfx,
                                               const float* sfy, char* ws) {
  __shared__ float sw[169], sx[169], sy[169];
  __shared__ double so[169];
  int t = threadIdx.x;
  if (t < 169) {
    float p = prm[t];
    float val = 1.f / (1.f + __expf(-8.f * p));
    float w = (val >= 0.001f) ? val : 0.f;
    double o = 0.0; float fx = 0.f, fy = 0.f;
    if (w > 0.f) {
      fx = sfx[t]; fy = sfy[t];
      double f2 = (double)fx*(double)fx + (double)fy*(double)fy;
      double num = 1.0 - 0.11390625 * f2;   // (M_RED*NA)^2
      double den = 1.0 - 0.87890625 * f2;   // (NA/N_LIQUID)^2
      o = (double)w * sqrt(num / den);      // w * obl^2
    }
    sw[t] = w; so[t] = o; sx[t] = fx; sy[t] = fy;
  }
  __syncthreads();
  if (t == 0) {
    float* wsf = (float*)ws; int* wsi = (int*)ws;
    double Sden = 0.0; int c = 0;
    for (int s = 0; s < 169; s++) {
      Sden += so[s];
      if (sw[s] > 0.f) { wsf[64+c] = sw[s]; wsf[320+c] = sx[s]; wsf[576+c] = sy[s]; c++; }
    }
    wsi[0] = c;
    wsf[1] = (float)(1.0 / (68719476736.0 * 1.44 * Sden)); // 1/(512^4*NL*Sden)
  }
}

// --- B1: row FFT of mask, keep window cols ---------------------------------
__global__ void __launch_bounds__(256) k_b1(const float* mask, float2* R1t) {
  int lane = threadIdx.x & 63, wv = threadIdx.x >> 6;
  int y = blockIdx.x * 4 + wv;                 // 0..511
  __shared__ float2 xch[4][512];
  __shared__ float2 twtab[512];
  build_tw<256>(twtab);
  float2 v[8];
  #pragma unroll
  for (int q = 0; q < 8; q++) v[q] = make_float2(mask[y*512 + 64*q + lane], 0.f);
  wfft512<-1>(v, lane, xch[wv], twtab);
  #pragma unroll
  for (int u = 0; u < 8; u++) {
    int k = (lane>>3) + 8*(lane&7) + 64*u;
    int beta = (k >= 392) ? (k - 392) : ((k <= 120) ? (k + 120) : -1);
    if (beta >= 0) R1t[beta*512 + y] = v[u];
  }
}

// --- B2: col FFT, keep window rows -> W[alpha][beta] -----------------------
__global__ void __launch_bounds__(256) k_b2(const float2* R1t, float2* Wg) {
  int lane = threadIdx.x & 63, wv = threadIdx.x >> 6;
  int j = blockIdx.x * 4 + wv;                 // beta, 0..243 (grid 61)
  __shared__ float2 xch[4][512];
  __shared__ float2 twtab[512];
  build_tw<256>(twtab);
  float2 v[8];
  #pragma unroll
  for (int q = 0; q < 8; q++)
    v[q] = (j < 241) ? R1t[j*512 + 64*q + lane] : make_float2(0.f, 0.f);
  wfft512<-1>(v, lane, xch[wv], twtab);
  if (j < 241) {
    #pragma unroll
    for (int u = 0; u < 8; u++) {
      int k = (lane>>3) + 8*(lane&7) + 64*u;
      int alpha = (k >= 392) ? (k - 392) : ((k <= 120) ? (k + 120) : -1);
      if (alpha >= 0) Wg[alpha*241 + j] = v[u];
    }
  }
}

// --- C1: per source, row IDFT of W.*P -> T2[s][x][alpha] -------------------
__global__ void __launch_bounds__(256) k_c1(const float2* Wg, const char* wsb,
                                            int base, float2* T2) {
  const int*   cnt = (const int*)wsb;
  const float* wsf = (const float*)wsb;
  int sic  = blockIdx.x / 31;
  int tile = blockIdx.x % 31;                  // 8 alphas per tile (31*8 >= 241)
  int slot = base + sic;
  if (slot >= *cnt) return;
  float fx = wsf[320 + slot], fy = wsf[576 + slot];
  int lane = threadIdx.x & 63, wv = threadIdx.x >> 6;
  __shared__ float2 xch[4][512];
  __shared__ float2 tout[8][512];
  __shared__ float2 twtab[512];
  build_tw<256>(twtab);
  #pragma unroll
  for (int i = 0; i < 2; i++) {
    int al = wv*2 + i;
    int alpha = tile*8 + al;
    double G = ((double)alpha - 120.0) * 0.01 + (double)fy;
    double g2 = G * G;
    float2 v[8];
    #pragma unroll
    for (int q = 0; q < 8; q++) {
      v[q] = make_float2(0.f, 0.f);
      int n = 64*q + lane;
      if (alpha < 241 && n < 241) {
        double F = ((double)n - 120.0) * 0.01 + (double)fx;
        double r2 = F*F + g2;
        if (r2 <= 1.0) {
          double num = 1.0 - 0.11390625 * r2;
          double den = 1.0 - 0.87890625 * r2;
          float P = (float)sqrt(sqrt(num / den));
          float2 Wv = Wg[alpha*241 + n];
          v[q] = make_float2(P * Wv.x, P * Wv.y);
        }
      }
    }
    wfft512<1>(v, lane, xch[wv], twtab);
    #pragma unroll
    for (int u = 0; u < 8; u++) {
      int xx = (lane>>3) + 8*(lane&7) + 64*u;
      tout[al][xx] = v[u];
    }
  }
  __syncthreads();
  #pragma unroll
  for (int r = 0; r < 2; r++) {
    int x = (int)threadIdx.x + 256*r;
    float2* dst = T2 + ((size_t)sic*512 + x)*244 + tile*8;
    #pragma unroll
    for (int jj = 0; jj < 8; jj++) {
      int col = tile*8 + jj;
      if (col < 244) dst[jj] = tout[jj][x];   // guard: no spill into next row
    }
  }
}

// --- C2: per source col IDFT, accumulate w*|AA|^2 --------------------------
__global__ void __launch_bounds__(64) k_c2(const float2* T2, const char* wsb,
                                           int base, int CH, float* accbuf) {
  const int*   cnt = (const int*)wsb;
  const float* wsf = (const float*)wsb;
  int x    = blockIdx.x >> 2;
  int part = blockIdx.x & 3;
  int lane = threadIdx.x;
  __shared__ float2 xch[512];
  __shared__ float2 twtab[512];
  build_tw<64>(twtab);
  float av[8] = {0.f,0.f,0.f,0.f,0.f,0.f,0.f,0.f};
  bool touched = false;
  int count = *cnt;
  for (int sic = part; sic < CH; sic += SPLIT) {
    int slot = base + sic;
    if (slot >= count) break;
    float w = wsf[64 + slot];
    float2 v[8];
    #pragma unroll
    for (int q = 0; q < 8; q++) v[q] = make_float2(0.f, 0.f);
    #pragma unroll
    for (int q = 0; q < 4; q++) {
      int n = 64*q + lane;
      if (n < 241) v[q] = T2[((size_t)sic*512 + x)*244 + n];
    }
    wfft512<1>(v, lane, xch, twtab);
    #pragma unroll
    for (int u = 0; u < 8; u++)
      av[u] = fmaf(w, fmaf(v[u].x, v[u].x, v[u].y*v[u].y), av[u]);
    touched = true;
  }
  if (touched) {
    float* a = accbuf + ((size_t)part << 18) + (size_t)x * 512;
    int y0 = (lane>>3) + 8*(lane&7);
    #pragma unroll
    for (int u = 0; u < 8; u++) a[y0 + 64*u] += av[u];
  }
}

// --- D: scale, doses, resist sigmoid ---------------------------------------
__global__ void __launch_bounds__(256) k_final(const float* acc, const char* wsb,
                                               float* out) {
  const float* wsf = (const float*)wsb;
  int tid = blockIdx.x * 256 + threadIdx.x;    // == y*512 + x
  int x = tid & 511, y = tid >> 9;
  float a = 0.f;
  #pragma unroll
  for (int p = 0; p < SPLIT; p++) a += acc[((size_t)p << 18) + x*512 + y];
  float I = a * wsf[1];
  const float dd[3] = {0.9604f, 1.0f, 1.0404f}; // dose^2
  #pragma unroll
  for (int k = 0; k < 3; k++) {
    float Ik = dd[k] * I;
    out[(size_t)k*262144 + tid] = Ik;
    out[(size_t)(3+k)*262144 + tid] = 1.f / (1.f + __expf(-30.f * (Ik - 0.225f)));
  }
}

extern "C" void kernel_launch(void* const* d_in, const int* in_sizes, int n_in,
                              void* d_out, int out_size, void* d_ws, size_t ws_size,
                              hipStream_t stream) {
  (void)in_sizes; (void)n_in; (void)out_size;
  const float* mask = (const float*)d_in[0];
  const float* prm  = (const float*)d_in[1];
  const float* sfx  = (const float*)d_in[2];
  const float* sfy  = (const float*)d_in[3];
  float* out = (float*)d_out;
  char*  ws  = (char*)d_ws;

  float*  acc = (float*)(ws + O_ACC);
  float2* Wg  = (float2*)(ws + O_WIN);
  float2* R1t = (float2*)(ws + O_R1);
  float2* T2  = (float2*)(ws + O_T2);

  hipMemsetAsync(acc, 0, ACC_BYTES, stream);
  k_setup<<<dim3(1),   dim3(256), 0, stream>>>(prm, sfx, sfy, ws);
  k_b1  <<<dim3(128), dim3(256), 0, stream>>>(mask, R1t);
  k_b2  <<<dim3(61),  dim3(256), 0, stream>>>(R1t, Wg);

  size_t avail = (ws_size > O_T2) ? (ws_size - O_T2) : 0;
  int CH = (int)(avail / SLOT_BYTES);
  if (CH > 169) CH = 169;
  if (CH < 1)   CH = 1;
  for (int base = 0; base < 169; base += CH) {
    k_c1<<<dim3((unsigned)(CH*31)),  dim3(256), 0, stream>>>(Wg, (const char*)ws, base, T2);
    k_c2<<<dim3(512*SPLIT),          dim3(64),  0, stream>>>(T2, (const char*)ws, base, CH, acc);
  }
  k_final<<<dim3(1024), dim3(256), 0, stream>>>(acc, (const char*)ws, out);
}

// Round 3
// 153.611 us; speedup vs baseline: 1.1055x; 1.1055x over previous
//
#include <hip/hip_runtime.h>
#include <hip/hip_bf16.h>

// ---------------------------------------------------------------------------
// Abbe lithography forward. Doses factor out (I(d)=d^2 I(1)); all shift
// phases cancel in |AA|^2; weight cancels against norm_I.
//   A : weights+compaction, scale, twiddle table (f64-built), FM grid
//   B1: row FFT of mask, keep 241 window cols  -> R1t[beta][y]
//   B2: col FFT, keep 241 window rows          -> W[alpha][beta]
//   C1: per source row IDFT of W.*P            -> T2[s][x][alpha]
//   C2: per source col IDFT, acc += w|AA|^2    -> acc[part][x][y]
//   D : scale, 3 doses, resist sigmoid (LDS-tiled transpose)
// FFT-512: radix-8, 3 stages, one wave per FFT. LDS exchanges use per-wave
// private buffers with wave-level ordering only (DS ops of a wave complete
// in order; wave_barrier pins compiler). Physical layouts chosen so writes
// are 2-way (free) and reads are contiguous b128:
//   exch A: PHY(u,l) = u*68 + (l&7)*8 + (l>>3); read base u0*68+p2*8
//   exch B: PHY(r,l) = r*68 + l;                read base p2*68+u0*8
// Output reg u of lane L holds X[(L>>3) + 8*(L&7) + 64*u].
// ---------------------------------------------------------------------------

#define SPLIT 4

static const size_t O_TW   = 4096;                       // float2[512]
static const size_t O_ACC  = 8192;                       // SPLIT*512*512*f32
static const size_t ACC_BYTES = (size_t)SPLIT * 512 * 512 * 4;
static const size_t O_WIN  = O_ACC + ACC_BYTES;          // 4202496
static const size_t O_R1   = O_WIN + 464896;             // 4667392
static const size_t O_T2   = O_R1 + 987136;              // 5654528
static const size_t SLOT_BYTES = (size_t)512 * 244 * 8;  // 999424

__device__ inline float2 cadd(float2 a, float2 b){ return make_float2(a.x+b.x, a.y+b.y); }
__device__ inline float2 csub(float2 a, float2 b){ return make_float2(a.x-b.x, a.y-b.y); }
__device__ inline float2 cmul(float2 a, float2 b){
  return make_float2(fmaf(a.x, b.x, -(a.y*b.y)), fmaf(a.x, b.y, a.y*b.x));
}
__device__ inline float2 twsgn(float2 t, int S) {
  return make_float2(t.x, (S > 0) ? t.y : -t.y);
}

template<int S>
__device__ inline void dft8(float2 v[8]) {
  const float sg = (float)S;
  const float C7 = 0.7071067811865476f;
  float2 t0=cadd(v[0],v[4]), t4=csub(v[0],v[4]);
  float2 t1=cadd(v[1],v[5]), t5=csub(v[1],v[5]);
  float2 t2=cadd(v[2],v[6]), t6=csub(v[2],v[6]);
  float2 t3=cadd(v[3],v[7]), t7=csub(v[3],v[7]);
  t5 = make_float2(C7*(t5.x - sg*t5.y), C7*(t5.y + sg*t5.x));
  t6 = make_float2(-sg*t6.y, sg*t6.x);
  t7 = make_float2(C7*(-t7.x - sg*t7.y), C7*(sg*t7.x - t7.y));
  float2 u0=cadd(t0,t2), u2=csub(t0,t2);
  float2 u1=cadd(t1,t3), u3=csub(t1,t3);
  u3 = make_float2(-sg*u3.y, sg*u3.x);
  float2 u4=cadd(t4,t6), u6=csub(t4,t6);
  float2 u5=cadd(t5,t7), u7=csub(t5,t7);
  u7 = make_float2(-sg*u7.y, sg*u7.x);
  v[0]=cadd(u0,u1); v[4]=csub(u0,u1);
  v[2]=cadd(u2,u3); v[6]=csub(u2,u3);
  v[1]=cadd(u4,u5); v[5]=csub(u4,u5);
  v[3]=cadd(u6,u7); v[7]=csub(u6,u7);
}

// One-wave FFT-512; xch = per-wave float2[544] (16B aligned). Wave-sync only.
template<int S>
__device__ inline void wfft512(float2 v[8], int lane, float2* xch,
                               const float2* twt) {
  const int p2 = lane & 7, u0 = lane >> 3;
  dft8<S>(v);
  { float2 t1 = twsgn(twt[lane], S), acc = t1;
    v[1] = cmul(v[1], acc);
    #pragma unroll
    for (int u = 2; u < 8; u++) { acc = cmul(acc, t1); v[u] = cmul(v[u], acc); } }
  __builtin_amdgcn_wave_barrier();
  #pragma unroll
  for (int u = 0; u < 8; u++) xch[u*68 + p2*8 + u0] = v[u];
  __builtin_amdgcn_wave_barrier();
  { const float4* rp = (const float4*)(xch + u0*68 + p2*8);
    #pragma unroll
    for (int q = 0; q < 4; q++) {
      float4 t = rp[q];
      v[2*q]   = make_float2(t.x, t.y);
      v[2*q+1] = make_float2(t.z, t.w);
    } }
  dft8<S>(v);
  { float2 t1 = twsgn(twt[p2 << 3], S), acc = t1;
    v[1] = cmul(v[1], acc);
    #pragma unroll
    for (int u = 2; u < 8; u++) { acc = cmul(acc, t1); v[u] = cmul(v[u], acc); } }
  __builtin_amdgcn_wave_barrier();
  #pragma unroll
  for (int u = 0; u < 8; u++) xch[u*68 + lane] = v[u];
  __builtin_amdgcn_wave_barrier();
  { const float4* rp = (const float4*)(xch + p2*68 + u0*8);
    #pragma unroll
    for (int q = 0; q < 4; q++) {
      float4 t = rp[q];
      v[2*q]   = make_float2(t.x, t.y);
      v[2*q+1] = make_float2(t.z, t.w);
    } }
  dft8<S>(v);
}

// --- A: weights, compaction, scale, twiddle + FM tables --------------------
__global__ void __launch_bounds__(256) k_setup(const float* prm, const float* sfx,
                                               const float* sfy, char* ws) {
  __shared__ float sw[169], sx[169], sy[169];
  __shared__ double so[169];
  int t = threadIdx.x;
  if (t < 169) {
    float p = prm[t];
    float val = 1.f / (1.f + __expf(-8.f * p));
    float w = (val >= 0.001f) ? val : 0.f;
    double o = 0.0; float fx = 0.f, fy = 0.f;
    if (w > 0.f) {
      fx = sfx[t]; fy = sfy[t];
      double f2 = (double)fx*(double)fx + (double)fy*(double)fy;
      o = (double)w * sqrt((1.0 - 0.11390625 * f2) / (1.0 - 0.87890625 * f2));
    }
    sw[t] = w; so[t] = o; sx[t] = fx; sy[t] = fy;
  }
  // twiddle table exp(+2*pi*i*k/512), double-built
  float2* gtw = (float2*)(ws + O_TW);
  for (int k = t; k < 512; k += 256) {
    double a = 6.283185307179586476925286766559 * (double)k / 512.0;
    gtw[k] = make_float2((float)cos(a), (float)sin(a));
  }
  // FM grid: (n-120)/100 rounded to f32 (matches np f64->f32 cast)
  if (t < 241) ((float*)ws)[768 + t] = (float)(((double)(t - 120)) / 100.0);
  __syncthreads();
  if (t == 0) {
    float* wsf = (float*)ws; int* wsi = (int*)ws;
    double Sden = 0.0; int c = 0;
    for (int s = 0; s < 169; s++) {
      Sden += so[s];
      if (sw[s] > 0.f) { wsf[64+c] = sw[s]; wsf[320+c] = sx[s]; wsf[576+c] = sy[s]; c++; }
    }
    wsi[0] = c;
    wsf[1] = (float)(1.0 / (68719476736.0 * 1.44 * Sden));
  }
}

// --- B1: row FFT of mask, keep window cols ---------------------------------
__global__ void __launch_bounds__(256, 6) k_b1(const float* mask, const char* wsb,
                                               float2* R1t) {
  int lane = threadIdx.x & 63, wv = threadIdx.x >> 6;
  int y = blockIdx.x * 4 + wv;
  __shared__ __align__(16) float2 lds[4*544];
  __shared__ __align__(16) float2 twt[512];
  ((float4*)twt)[threadIdx.x] = ((const float4*)(wsb + O_TW))[threadIdx.x];
  __syncthreads();
  float2 v[8];
  #pragma unroll
  for (int q = 0; q < 8; q++) v[q] = make_float2(mask[y*512 + 64*q + lane], 0.f);
  wfft512<-1>(v, lane, lds + wv*544, twt);
  #pragma unroll
  for (int u = 0; u < 8; u++) {
    int k = (lane>>3) + 8*(lane&7) + 64*u;
    int beta = (k >= 392) ? (k - 392) : ((k <= 120) ? (k + 120) : -1);
    if (beta >= 0) R1t[beta*512 + y] = v[u];
  }
}

// --- B2: col FFT, keep window rows -> W[alpha][beta] -----------------------
__global__ void __launch_bounds__(256, 6) k_b2(const float2* R1t, const char* wsb,
                                               float2* Wg) {
  int lane = threadIdx.x & 63, wv = threadIdx.x >> 6;
  int j = blockIdx.x * 4 + wv;                 // beta, grid 61 -> 0..243
  __shared__ __align__(16) float2 lds[4*544];
  __shared__ __align__(16) float2 twt[512];
  ((float4*)twt)[threadIdx.x] = ((const float4*)(wsb + O_TW))[threadIdx.x];
  __syncthreads();
  float2 v[8];
  #pragma unroll
  for (int q = 0; q < 8; q++)
    v[q] = (j < 241) ? R1t[j*512 + 64*q + lane] : make_float2(0.f, 0.f);
  wfft512<-1>(v, lane, lds + wv*544, twt);
  if (j < 241) {
    #pragma unroll
    for (int u = 0; u < 8; u++) {
      int k = (lane>>3) + 8*(lane&7) + 64*u;
      int alpha = (k >= 392) ? (k - 392) : ((k <= 120) ? (k + 120) : -1);
      if (alpha >= 0) Wg[alpha*241 + j] = v[u];
    }
  }
}

// --- C1: per source row IDFT of W.*P -> T2[s][x][alpha] --------------------
__global__ void __launch_bounds__(256, 6) k_c1(const float2* Wg, const char* wsb,
                                               int base, float2* T2) {
  const int*   cnt = (const int*)wsb;
  const float* wsf = (const float*)wsb;
  const float* FMt = (const float*)(wsb + 3072);
  int sic  = blockIdx.x / 31;
  int tile = blockIdx.x % 31;                  // 8 alphas/tile, 2 phases of 4
  int slot = base + sic;
  if (slot >= *cnt) return;
  __shared__ __align__(16) float2 lds[4*544];  // per-wave xch, reused as tout
  __shared__ __align__(16) float2 twt[512];
  ((float4*)twt)[threadIdx.x] = ((const float4*)(wsb + O_TW))[threadIdx.x];
  __syncthreads();
  float fx = wsf[320 + slot], fy = wsf[576 + slot];
  int lane = threadIdx.x & 63, wv = threadIdx.x >> 6;
  float2* xch = lds + wv*544;
  #pragma unroll
  for (int ph = 0; ph < 2; ph++) {
    int alpha = tile*8 + ph*4 + wv;
    bool arow = (alpha < 241);
    float Gf = __fadd_rn(arow ? FMt[alpha] : 0.f, fy);
    float g2 = __fmul_rn(Gf, Gf);
    float2 v[8];
    #pragma unroll
    for (int q = 0; q < 8; q++) {
      int n = 64*q + lane;
      float2 val = make_float2(0.f, 0.f);
      if (arow && n < 241) {
        float Ff = __fadd_rn(FMt[n], fx);
        float r2 = __fadd_rn(__fmul_rn(Ff, Ff), g2);   // np f32 semantics
        if (r2 <= 1.0f) {
          float num = fmaf(-0.11390625f, r2, 1.0f);
          float den = fmaf(-0.87890625f, r2, 1.0f);
          float P = __fsqrt_rn(__fsqrt_rn(__fdividef(num, den)));
          float2 Wv = Wg[alpha*241 + n];
          val = make_float2(P * Wv.x, P * Wv.y);
        }
      }
      v[q] = val;
    }
    wfft512<1>(v, lane, xch, twt);
    // stash into own (dead) xch region as tout[wv][x]
    #pragma unroll
    for (int u = 0; u < 8; u++) {
      int xx = (lane>>3) + 8*(lane&7) + 64*u;
      xch[xx] = v[u];
    }
    __syncthreads();
    int colb = tile*8 + ph*4;
    if (colb < 244) {                          // tile30/ph1 would spill: skip
      #pragma unroll
      for (int r = 0; r < 2; r++) {
        int x = (int)threadIdx.x + 256*r;
        float2 a0 = lds[0*544+x], a1 = lds[1*544+x];
        float2 a2 = lds[2*544+x], a3 = lds[3*544+x];
        float4* dst = (float4*)(T2 + ((size_t)sic*512 + x)*244 + colb);
        dst[0] = make_float4(a0.x, a0.y, a1.x, a1.y);
        dst[1] = make_float4(a2.x, a2.y, a3.x, a3.y);
      }
    }
    __syncthreads();
  }
}

// --- C2: per source col IDFT, acc += w*|AA|^2 ------------------------------
__global__ void __launch_bounds__(64, 4) k_c2(const float2* T2, const char* wsb,
                                              int base, int CH, int first,
                                              float* accbuf) {
  const int*   cnt = (const int*)wsb;
  const float* wsf = (const float*)wsb;
  int x    = blockIdx.x >> 2;
  int part = blockIdx.x & 3;
  int lane = threadIdx.x;
  __shared__ __align__(16) float2 xch[544];
  __shared__ __align__(16) float2 twt[512];
  #pragma unroll
  for (int i = 0; i < 4; i++)
    ((float4*)twt)[lane + 64*i] = ((const float4*)(wsb + O_TW))[lane + 64*i];
  __builtin_amdgcn_wave_barrier();
  int count = *cnt;
  float av[8] = {0.f,0.f,0.f,0.f,0.f,0.f,0.f,0.f};
  bool touched = false;
  int sic = part;
  bool act = (sic < CH) && (base + sic < count);
  float2 pv[4] = {{0.f,0.f},{0.f,0.f},{0.f,0.f},{0.f,0.f}};
  if (act) {
    const float2* row = T2 + ((size_t)sic*512 + x)*244;
    #pragma unroll
    for (int q = 0; q < 4; q++) {
      int n = 64*q + lane;
      pv[q] = (n < 241) ? row[n] : make_float2(0.f, 0.f);
    }
  }
  while (act) {
    float w = wsf[64 + base + sic];
    float2 v[8];
    #pragma unroll
    for (int q = 0; q < 4; q++) v[q] = pv[q];
    #pragma unroll
    for (int q = 4; q < 8; q++) v[q] = make_float2(0.f, 0.f);
    int nsic = sic + SPLIT;
    act = (nsic < CH) && (base + nsic < count);
    if (act) {                                  // prefetch across the FFT
      const float2* row = T2 + ((size_t)nsic*512 + x)*244;
      #pragma unroll
      for (int q = 0; q < 4; q++) {
        int n = 64*q + lane;
        pv[q] = (n < 241) ? row[n] : make_float2(0.f, 0.f);
      }
    }
    wfft512<1>(v, lane, xch, twt);
    #pragma unroll
    for (int u = 0; u < 8; u++)
      av[u] = fmaf(w, fmaf(v[u].x, v[u].x, v[u].y*v[u].y), av[u]);
    touched = true;
    sic = nsic;
  }
  float* a = accbuf + ((size_t)part << 18) + (size_t)x * 512;
  int y0 = (lane>>3) + 8*(lane&7);
  if (first) {
    #pragma unroll
    for (int u = 0; u < 8; u++) a[y0 + 64*u] = av[u];
  } else if (touched) {
    #pragma unroll
    for (int u = 0; u < 8; u++) a[y0 + 64*u] += av[u];
  }
}

// --- D: transpose-tile, scale, doses, resist sigmoid -----------------------
__global__ void __launch_bounds__(256) k_final(const float* acc, const char* wsb,
                                               float* out) {
  __shared__ float tile[64][65];
  const float* wsf = (const float*)wsb;
  float scale = wsf[1];
  int x0 = (blockIdx.x & 7) * 64, y0 = (blockIdx.x >> 3) * 64;
  int j = threadIdx.x & 63, i0 = threadIdx.x >> 6;
  #pragma unroll
  for (int k = 0; k < 16; k++) {
    int i = i0 + 4*k;
    const float* ap = acc + (size_t)(x0 + i)*512 + y0 + j;
    tile[i][j] = ap[0] + ap[1<<18] + ap[2<<18] + ap[3<<18];
  }
  __syncthreads();
  const float dd[3] = {0.9604f, 1.0f, 1.0404f};
  #pragma unroll
  for (int k = 0; k < 16; k++) {
    int yy = i0 + 4*k;
    float I = scale * tile[j][yy];
    int o = (y0 + yy)*512 + x0 + j;
    #pragma unroll
    for (int d = 0; d < 3; d++) {
      float Ik = dd[d] * I;
      out[(size_t)d*262144 + o] = Ik;
      out[(size_t)(3+d)*262144 + o] = 1.f / (1.f + __expf(-30.f*(Ik - 0.225f)));
    }
  }
}

extern "C" void kernel_launch(void* const* d_in, const int* in_sizes, int n_in,
                              void* d_out, int out_size, void* d_ws, size_t ws_size,
                              hipStream_t stream) {
  (void)in_sizes; (void)n_in; (void)out_size;
  const float* mask = (const float*)d_in[0];
  const float* prm  = (const float*)d_in[1];
  const float* sfx  = (const float*)d_in[2];
  const float* sfy  = (const float*)d_in[3];
  float* out = (float*)d_out;
  char*  ws  = (char*)d_ws;

  float*  acc = (float*)(ws + O_ACC);
  float2* Wg  = (float2*)(ws + O_WIN);
  float2* R1t = (float2*)(ws + O_R1);
  float2* T2  = (float2*)(ws + O_T2);

  k_setup<<<dim3(1),   dim3(256), 0, stream>>>(prm, sfx, sfy, ws);
  k_b1  <<<dim3(128), dim3(256), 0, stream>>>(mask, (const char*)ws, R1t);
  k_b2  <<<dim3(61),  dim3(256), 0, stream>>>(R1t, (const char*)ws, Wg);

  size_t avail = (ws_size > O_T2) ? (ws_size - O_T2) : 0;
  int CH = (int)(avail / SLOT_BYTES);
  if (CH > 169) CH = 169;
  if (CH < 1)   CH = 1;
  for (int base = 0; base < 169; base += CH) {
    k_c1<<<dim3((unsigned)(CH*31)), dim3(256), 0, stream>>>(Wg, (const char*)ws, base, T2);
    k_c2<<<dim3(512*SPLIT),         dim3(64),  0, stream>>>(T2, (const char*)ws, base, CH,
                                                            (base == 0) ? 1 : 0, acc);
  }
  k_final<<<dim3(64), dim3(256), 0, stream>>>(acc, (const char*)ws, out);
}

// Round 4
// 147.371 us; speedup vs baseline: 1.1523x; 1.0423x over previous
//
#include <hip/hip_runtime.h>
#include <hip/hip_bf16.h>
#include <hip/hip_fp16.h>

// ---------------------------------------------------------------------------
// Abbe lithography forward. Doses factor out (I(d)=d^2 I(1)); all shift
// phases cancel in |AA|^2; weight cancels against norm_I.
//   A : weights+compaction, scale, twiddle table (f64-built), FM grid
//   B1: row FFT of mask, keep 241 window cols  -> R1t[beta][y]
//   B2: col FFT, keep 241 window rows          -> W[alpha][beta]
//   C1: per source row IDFT of (W.*P)/512      -> T2[s][x][alpha]  (fp16 cplx)
//   C2: per source col IDFT, acc += w|AA|^2    -> acc[part][x][y]
//   D : scale (x512^2 refold), 3 doses, resist sigmoid (LDS transpose)
// FFT-512: radix-8, 3 stages, one wave per FFT, wave-level sync only.
// Exchange layouts: writes 2-way (free), reads contiguous ds_read_b128.
// Output reg u of lane L holds X[(L>>3) + 8*(L&7) + 64*u].
// ---------------------------------------------------------------------------

#define SPLIT 8

static const size_t O_TW   = 4096;                       // float2[512]
static const size_t O_ACC  = 8192;                       // SPLIT*512*512*f32
static const size_t ACC_BYTES = (size_t)SPLIT * 512 * 512 * 4;
static const size_t O_WIN  = O_ACC + ACC_BYTES;
static const size_t O_R1   = O_WIN + 464896;
static const size_t O_T2   = O_R1 + 987136;
static const size_t SLOT_BYTES = (size_t)512 * 244 * 4;  // half2 slots

__device__ inline float2 cadd(float2 a, float2 b){ return make_float2(a.x+b.x, a.y+b.y); }
__device__ inline float2 csub(float2 a, float2 b){ return make_float2(a.x-b.x, a.y-b.y); }
__device__ inline float2 cmul(float2 a, float2 b){
  return make_float2(fmaf(a.x, b.x, -(a.y*b.y)), fmaf(a.x, b.y, a.y*b.x));
}
__device__ inline float2 twsgn(float2 t, int S) {
  return make_float2(t.x, (S > 0) ? t.y : -t.y);
}

// Radix-8 butterfly. If ZTOP, v[4..7] are known zero (skips first add level).
template<int S, bool ZTOP>
__device__ inline void dft8(float2 v[8]) {
  const float sg = (float)S;
  const float C7 = 0.7071067811865476f;
  float2 t0, t1, t2, t3, t4, t5, t6, t7;
  if (ZTOP) {
    t0 = v[0]; t4 = v[0];
    t1 = v[1]; t5 = v[1];
    t2 = v[2]; t6 = v[2];
    t3 = v[3]; t7 = v[3];
  } else {
    t0=cadd(v[0],v[4]); t4=csub(v[0],v[4]);
    t1=cadd(v[1],v[5]); t5=csub(v[1],v[5]);
    t2=cadd(v[2],v[6]); t6=csub(v[2],v[6]);
    t3=cadd(v[3],v[7]); t7=csub(v[3],v[7]);
  }
  t5 = make_float2(C7*(t5.x - sg*t5.y), C7*(t5.y + sg*t5.x));
  t6 = make_float2(-sg*t6.y, sg*t6.x);
  t7 = make_float2(C7*(-t7.x - sg*t7.y), C7*(sg*t7.x - t7.y));
  float2 u0=cadd(t0,t2), u2=csub(t0,t2);
  float2 u1=cadd(t1,t3), u3=csub(t1,t3);
  u3 = make_float2(-sg*u3.y, sg*u3.x);
  float2 u4=cadd(t4,t6), u6=csub(t4,t6);
  float2 u5=cadd(t5,t7), u7=csub(t5,t7);
  u7 = make_float2(-sg*u7.y, sg*u7.x);
  v[0]=cadd(u0,u1); v[4]=csub(u0,u1);
  v[2]=cadd(u2,u3); v[6]=csub(u2,u3);
  v[1]=cadd(u4,u5); v[5]=csub(u4,u5);
  v[3]=cadd(u6,u7); v[7]=csub(u6,u7);
}

// One-wave FFT-512; xch = per-wave float2[544] (16B aligned). Wave-sync only.
template<int S, bool ZTOP>
__device__ inline void wfft512(float2 v[8], int lane, float2* xch,
                               const float2* twt) {
  const int p2 = lane & 7, u0 = lane >> 3;
  dft8<S, ZTOP>(v);
  { float2 t1 = twsgn(twt[lane], S), acc = t1;
    v[1] = cmul(v[1], acc);
    #pragma unroll
    for (int u = 2; u < 8; u++) { acc = cmul(acc, t1); v[u] = cmul(v[u], acc); } }
  __builtin_amdgcn_wave_barrier();
  #pragma unroll
  for (int u = 0; u < 8; u++) xch[u*68 + p2*8 + u0] = v[u];
  __builtin_amdgcn_wave_barrier();
  { const float4* rp = (const float4*)(xch + u0*68 + p2*8);
    #pragma unroll
    for (int q = 0; q < 4; q++) {
      float4 t = rp[q];
      v[2*q]   = make_float2(t.x, t.y);
      v[2*q+1] = make_float2(t.z, t.w);
    } }
  dft8<S, false>(v);
  { float2 t1 = twsgn(twt[p2 << 3], S), acc = t1;
    v[1] = cmul(v[1], acc);
    #pragma unroll
    for (int u = 2; u < 8; u++) { acc = cmul(acc, t1); v[u] = cmul(v[u], acc); } }
  __builtin_amdgcn_wave_barrier();
  #pragma unroll
  for (int u = 0; u < 8; u++) xch[u*68 + lane] = v[u];
  __builtin_amdgcn_wave_barrier();
  { const float4* rp = (const float4*)(xch + p2*68 + u0*8);
    #pragma unroll
    for (int q = 0; q < 4; q++) {
      float4 t = rp[q];
      v[2*q]   = make_float2(t.x, t.y);
      v[2*q+1] = make_float2(t.z, t.w);
    } }
  dft8<S, false>(v);
}

// --- A: weights, compaction, scale, twiddle + FM tables --------------------
__global__ void __launch_bounds__(256) k_setup(const float* prm, const float* sfx,
                                               const float* sfy, char* ws) {
  __shared__ float sw[169], sx[169], sy[169];
  __shared__ double so[169];
  int t = threadIdx.x;
  if (t < 169) {
    float p = prm[t];
    float val = 1.f / (1.f + __expf(-8.f * p));
    float w = (val >= 0.001f) ? val : 0.f;
    double o = 0.0; float fx = 0.f, fy = 0.f;
    if (w > 0.f) {
      fx = sfx[t]; fy = sfy[t];
      double f2 = (double)fx*(double)fx + (double)fy*(double)fy;
      o = (double)w * sqrt((1.0 - 0.11390625 * f2) / (1.0 - 0.87890625 * f2));
    }
    sw[t] = w; so[t] = o; sx[t] = fx; sy[t] = fy;
  }
  float2* gtw = (float2*)(ws + O_TW);
  for (int k = t; k < 512; k += 256) {
    double a = 6.283185307179586476925286766559 * (double)k / 512.0;
    gtw[k] = make_float2((float)cos(a), (float)sin(a));
  }
  if (t < 241) ((float*)ws)[768 + t] = (float)(((double)(t - 120)) / 100.0);
  __syncthreads();
  if (t == 0) {
    float* wsf = (float*)ws; int* wsi = (int*)ws;
    double Sden = 0.0; int c = 0;
    for (int s = 0; s < 169; s++) {
      Sden += so[s];
      if (sw[s] > 0.f) { wsf[64+c] = sw[s]; wsf[320+c] = sx[s]; wsf[576+c] = sy[s]; c++; }
    }
    wsi[0] = c;
    // final scale, with T2's 1/512 pre-scale refolded (512^2):
    wsf[1] = (float)(1.0 / (262144.0 * 1.44 * Sden));
  }
}

// --- B1: row FFT of mask, keep window cols ---------------------------------
__global__ void __launch_bounds__(256, 6) k_b1(const float* mask, const char* wsb,
                                               float2* R1t) {
  int lane = threadIdx.x & 63, wv = threadIdx.x >> 6;
  int y = blockIdx.x * 4 + wv;
  __shared__ __align__(16) float2 lds[4*544];
  __shared__ __align__(16) float2 twt[512];
  ((float4*)twt)[threadIdx.x] = ((const float4*)(wsb + O_TW))[threadIdx.x];
  __syncthreads();
  float2 v[8];
  #pragma unroll
  for (int q = 0; q < 8; q++) v[q] = make_float2(mask[y*512 + 64*q + lane], 0.f);
  wfft512<-1, false>(v, lane, lds + wv*544, twt);
  #pragma unroll
  for (int u = 0; u < 8; u++) {
    int k = (lane>>3) + 8*(lane&7) + 64*u;
    int beta = (k >= 392) ? (k - 392) : ((k <= 120) ? (k + 120) : -1);
    if (beta >= 0) R1t[beta*512 + y] = v[u];
  }
}

// --- B2: col FFT, keep window rows -> W[alpha][beta] -----------------------
__global__ void __launch_bounds__(256, 6) k_b2(const float2* R1t, const char* wsb,
                                               float2* Wg) {
  int lane = threadIdx.x & 63, wv = threadIdx.x >> 6;
  int j = blockIdx.x * 4 + wv;                 // beta, grid 61 -> 0..243
  __shared__ __align__(16) float2 lds[4*544];
  __shared__ __align__(16) float2 twt[512];
  ((float4*)twt)[threadIdx.x] = ((const float4*)(wsb + O_TW))[threadIdx.x];
  __syncthreads();
  float2 v[8];
  #pragma unroll
  for (int q = 0; q < 8; q++)
    v[q] = (j < 241) ? R1t[j*512 + 64*q + lane] : make_float2(0.f, 0.f);
  wfft512<-1, false>(v, lane, lds + wv*544, twt);
  if (j < 241) {
    #pragma unroll
    for (int u = 0; u < 8; u++) {
      int k = (lane>>3) + 8*(lane&7) + 64*u;
      int alpha = (k >= 392) ? (k - 392) : ((k <= 120) ? (k + 120) : -1);
      if (alpha >= 0) Wg[alpha*241 + j] = v[u];
    }
  }
}

// --- C1: per source row IDFT of (W.*P)/512 -> T2[s][x][alpha] (half2) ------
__global__ void __launch_bounds__(256, 7) k_c1(const float2* Wg, const char* wsb,
                                               int base, __half2* T2) {
  const int*   cnt = (const int*)wsb;
  const float* wsf = (const float*)wsb;
  const float* FMt = (const float*)(wsb + 3072);
  int sic  = blockIdx.x / 31;
  int tile = blockIdx.x % 31;                  // 8 alphas/tile, 2 phases of 4
  int slot = base + sic;
  if (slot >= *cnt) return;
  __shared__ __align__(16) float2 lds[4*544];  // per-wave xch, reused as tout
  __shared__ __align__(16) float2 twt[512];
  ((float4*)twt)[threadIdx.x] = ((const float4*)(wsb + O_TW))[threadIdx.x];
  __syncthreads();
  float fx = wsf[320 + slot], fy = wsf[576 + slot];
  int lane = threadIdx.x & 63, wv = threadIdx.x >> 6;
  float2* xch = lds + wv*544;
  #pragma unroll
  for (int ph = 0; ph < 2; ph++) {
    int alpha = tile*8 + ph*4 + wv;
    bool arow = (alpha < 241);
    float Gf = __fadd_rn(arow ? FMt[alpha] : 0.f, fy);
    float g2 = __fmul_rn(Gf, Gf);
    float2 v[8];
    #pragma unroll
    for (int q = 0; q < 8; q++) {
      int n = 64*q + lane;
      float2 val = make_float2(0.f, 0.f);
      if (arow && n < 241) {
        float Ff = __fadd_rn(FMt[n], fx);
        float r2 = __fadd_rn(__fmul_rn(Ff, Ff), g2);   // np f32 semantics
        if (r2 <= 1.0f) {
          float num = fmaf(-0.11390625f, r2, 1.0f);
          float den = fmaf(-0.87890625f, r2, 1.0f);
          float P = __fsqrt_rn(__fsqrt_rn(__fdividef(num, den)))
                    * 0.001953125f;            // 1/512 pre-scale for fp16 T2
          float2 Wv = Wg[alpha*241 + n];
          val = make_float2(P * Wv.x, P * Wv.y);
        }
      }
      v[q] = val;
    }
    wfft512<1, false>(v, lane, xch, twt);
    #pragma unroll
    for (int u = 0; u < 8; u++) {
      int xx = (lane>>3) + 8*(lane&7) + 64*u;
      xch[xx] = v[u];
    }
    __syncthreads();
    int colb = tile*8 + ph*4;
    if (colb < 244) {                          // tile30/ph1 would spill: skip
      #pragma unroll
      for (int r = 0; r < 2; r++) {
        int x = (int)threadIdx.x + 256*r;
        union { __half2 h[4]; float4 f; } u;
        #pragma unroll
        for (int wvi = 0; wvi < 4; wvi++) {
          float2 a = lds[wvi*544 + x];
          u.h[wvi] = __floats2half2_rn(a.x, a.y);
        }
        *(float4*)(T2 + ((size_t)sic*512 + x)*244 + colb) = u.f;
      }
    }
    __syncthreads();
  }
}

// --- C2: per source col IDFT, acc += w*|AA|^2 ------------------------------
__global__ void __launch_bounds__(64, 8) k_c2(const __half2* T2, const char* wsb,
                                              int base, int CH, int first,
                                              float* accbuf) {
  const int*   cnt = (const int*)wsb;
  const float* wsf = (const float*)wsb;
  int x    = blockIdx.x >> 3;
  int part = blockIdx.x & (SPLIT-1);
  int lane = threadIdx.x;
  __shared__ __align__(16) float2 xch[544];
  __shared__ __align__(16) float2 twt[512];
  #pragma unroll
  for (int i = 0; i < 4; i++)
    ((float4*)twt)[lane + 64*i] = ((const float4*)(wsb + O_TW))[lane + 64*i];
  __builtin_amdgcn_wave_barrier();
  int count = *cnt;
  float av[8] = {0.f,0.f,0.f,0.f,0.f,0.f,0.f,0.f};
  int sic = part;
  bool act = (sic < CH) && (base + sic < count);
  __half2 pv[4] = {{0.f,0.f},{0.f,0.f},{0.f,0.f},{0.f,0.f}};
  if (act) {
    const __half2* row = T2 + ((size_t)sic*512 + x)*244;
    #pragma unroll
    for (int q = 0; q < 4; q++) {
      int n = 64*q + lane;
      pv[q] = (n < 241) ? row[n] : __half2{0.f, 0.f};
    }
  }
  while (act) {
    float w = wsf[64 + base + sic];
    float2 v[8];
    #pragma unroll
    for (int q = 0; q < 4; q++) { float2 f = __half22float2(pv[q]); v[q] = f; }
    #pragma unroll
    for (int q = 4; q < 8; q++) v[q] = make_float2(0.f, 0.f);
    int nsic = sic + SPLIT;
    act = (nsic < CH) && (base + nsic < count);
    if (act) {                                  // prefetch across the FFT
      const __half2* row = T2 + ((size_t)nsic*512 + x)*244;
      #pragma unroll
      for (int q = 0; q < 4; q++) {
        int n = 64*q + lane;
        pv[q] = (n < 241) ? row[n] : __half2{0.f, 0.f};
      }
    }
    wfft512<1, true>(v, lane, xch, twt);
    #pragma unroll
    for (int u = 0; u < 8; u++)
      av[u] = fmaf(w, fmaf(v[u].x, v[u].x, v[u].y*v[u].y), av[u]);
    sic = nsic;
  }
  float* a = accbuf + ((size_t)part << 18) + (size_t)x * 512;
  int y0 = (lane>>3) + 8*(lane&7);
  if (first) {
    #pragma unroll
    for (int u = 0; u < 8; u++) a[y0 + 64*u] = av[u];
  } else {
    #pragma unroll
    for (int u = 0; u < 8; u++) a[y0 + 64*u] += av[u];
  }
}

// --- D: transpose-tile, scale, doses, resist sigmoid -----------------------
__global__ void __launch_bounds__(256) k_final(const float* acc, const char* wsb,
                                               float* out) {
  __shared__ float tile[64][65];
  const float* wsf = (const float*)wsb;
  float scale = wsf[1];
  int x0 = (blockIdx.x & 7) * 64, y0 = (blockIdx.x >> 3) * 64;
  int j = threadIdx.x & 63, i0 = threadIdx.x >> 6;
  #pragma unroll
  for (int k = 0; k < 16; k++) {
    int i = i0 + 4*k;
    const float* ap = acc + (size_t)(x0 + i)*512 + y0 + j;
    float s = 0.f;
    #pragma unroll
    for (int p = 0; p < SPLIT; p++) s += ap[(size_t)p << 18];
    tile[i][j] = s;
  }
  __syncthreads();
  const float dd[3] = {0.9604f, 1.0f, 1.0404f};
  #pragma unroll
  for (int k = 0; k < 16; k++) {
    int yy = i0 + 4*k;
    float I = scale * tile[j][yy];
    int o = (y0 + yy)*512 + x0 + j;
    #pragma unroll
    for (int d = 0; d < 3; d++) {
      float Ik = dd[d] * I;
      out[(size_t)d*262144 + o] = Ik;
      out[(size_t)(3+d)*262144 + o] = 1.f / (1.f + __expf(-30.f*(Ik - 0.225f)));
    }
  }
}

extern "C" void kernel_launch(void* const* d_in, const int* in_sizes, int n_in,
                              void* d_out, int out_size, void* d_ws, size_t ws_size,
                              hipStream_t stream) {
  (void)in_sizes; (void)n_in; (void)out_size;
  const float* mask = (const float*)d_in[0];
  const float* prm  = (const float*)d_in[1];
  const float* sfx  = (const float*)d_in[2];
  const float* sfy  = (const float*)d_in[3];
  float* out = (float*)d_out;
  char*  ws  = (char*)d_ws;

  float*   acc = (float*)(ws + O_ACC);
  float2*  Wg  = (float2*)(ws + O_WIN);
  float2*  R1t = (float2*)(ws + O_R1);
  __half2* T2  = (__half2*)(ws + O_T2);

  k_setup<<<dim3(1),   dim3(256), 0, stream>>>(prm, sfx, sfy, ws);
  k_b1  <<<dim3(128), dim3(256), 0, stream>>>(mask, (const char*)ws, R1t);
  k_b2  <<<dim3(61),  dim3(256), 0, stream>>>(R1t, (const char*)ws, Wg);

  size_t avail = (ws_size > O_T2) ? (ws_size - O_T2) : 0;
  int CH = (int)(avail / SLOT_BYTES);
  if (CH > 169) CH = 169;
  if (CH < 1)   CH = 1;
  for (int base = 0; base < 169; base += CH) {
    k_c1<<<dim3((unsigned)(CH*31)), dim3(256), 0, stream>>>(Wg, (const char*)ws, base, T2);
    k_c2<<<dim3(512*SPLIT),         dim3(64),  0, stream>>>(T2, (const char*)ws, base, CH,
                                                            (base == 0) ? 1 : 0, acc);
  }
  k_final<<<dim3(64), dim3(256), 0, stream>>>(acc, (const char*)ws, out);
}

// Round 5
// 142.243 us; speedup vs baseline: 1.1939x; 1.0361x over previous
//
#include <hip/hip_runtime.h>
#include <hip/hip_bf16.h>
#include <hip/hip_fp16.h>

// ---------------------------------------------------------------------------
// Abbe lithography forward. Doses factor out (I(d)=d^2 I(1)); all shift
// phases cancel in |AA|^2; weight cancels against norm_I.
//   A : weights+compaction, scale, twiddle table (f64-built), FM grid
//   B1: row FFT of mask, keep 241 window cols  -> R1t[beta][y]
//   B2: col FFT, keep 241 window rows          -> W[alpha][beta]
//   C1: per source row IDFT of (W.*P)*sqrt(w)/512 -> T2[s][x][alpha] (fp16)
//       rows with fl(G^2)>1 are provably all-zero (monotone rounding) ->
//       skip the FFT for those waves, store zeros.
//   C2: per source col IDFT, acc += |AA'|^2    -> acc[part][x][y]
//   D : scale (x512^2 refold), 3 doses, resist sigmoid (LDS transpose)
// FFT-512: radix-8, 3 stages, one wave per FFT, wave-level sync only.
// Exchange layouts: writes 2-way (free), reads contiguous ds_read_b128.
// Output reg u of lane L holds X[(L>>3) + 8*(L&7) + 64*u].
// ---------------------------------------------------------------------------

#define SPLIT 8

static const size_t O_TW   = 4096;                       // float2[512]
static const size_t O_ACC  = 8192;                       // SPLIT*512*512*f32
static const size_t ACC_BYTES = (size_t)SPLIT * 512 * 512 * 4;
static const size_t O_WIN  = O_ACC + ACC_BYTES;
static const size_t O_R1   = O_WIN + 464896;
static const size_t O_T2   = O_R1 + 987136;
static const size_t SLOT_BYTES = (size_t)512 * 244 * 4;  // half2 slots

__device__ inline float2 cadd(float2 a, float2 b){ return make_float2(a.x+b.x, a.y+b.y); }
__device__ inline float2 csub(float2 a, float2 b){ return make_float2(a.x-b.x, a.y-b.y); }
__device__ inline float2 cmul(float2 a, float2 b){
  return make_float2(fmaf(a.x, b.x, -(a.y*b.y)), fmaf(a.x, b.y, a.y*b.x));
}
__device__ inline float2 twsgn(float2 t, int S) {
  return make_float2(t.x, (S > 0) ? t.y : -t.y);
}

// Radix-8 butterfly. If ZTOP, v[4..7] are known zero (skips first add level).
template<int S, bool ZTOP>
__device__ inline void dft8(float2 v[8]) {
  const float sg = (float)S;
  const float C7 = 0.7071067811865476f;
  float2 t0, t1, t2, t3, t4, t5, t6, t7;
  if (ZTOP) {
    t0 = v[0]; t4 = v[0];
    t1 = v[1]; t5 = v[1];
    t2 = v[2]; t6 = v[2];
    t3 = v[3]; t7 = v[3];
  } else {
    t0=cadd(v[0],v[4]); t4=csub(v[0],v[4]);
    t1=cadd(v[1],v[5]); t5=csub(v[1],v[5]);
    t2=cadd(v[2],v[6]); t6=csub(v[2],v[6]);
    t3=cadd(v[3],v[7]); t7=csub(v[3],v[7]);
  }
  t5 = make_float2(C7*(t5.x - sg*t5.y), C7*(t5.y + sg*t5.x));
  t6 = make_float2(-sg*t6.y, sg*t6.x);
  t7 = make_float2(C7*(-t7.x - sg*t7.y), C7*(sg*t7.x - t7.y));
  float2 u0=cadd(t0,t2), u2=csub(t0,t2);
  float2 u1=cadd(t1,t3), u3=csub(t1,t3);
  u3 = make_float2(-sg*u3.y, sg*u3.x);
  float2 u4=cadd(t4,t6), u6=csub(t4,t6);
  float2 u5=cadd(t5,t7), u7=csub(t5,t7);
  u7 = make_float2(-sg*u7.y, sg*u7.x);
  v[0]=cadd(u0,u1); v[4]=csub(u0,u1);
  v[2]=cadd(u2,u3); v[6]=csub(u2,u3);
  v[1]=cadd(u4,u5); v[5]=csub(u4,u5);
  v[3]=cadd(u6,u7); v[7]=csub(u6,u7);
}

// One-wave FFT-512; xch = per-wave float2[544] (16B aligned). Wave-sync only.
template<int S, bool ZTOP>
__device__ inline void wfft512(float2 v[8], int lane, float2* xch,
                               const float2* twt) {
  const int p2 = lane & 7, u0 = lane >> 3;
  dft8<S, ZTOP>(v);
  { float2 t1 = twsgn(twt[lane], S), acc = t1;
    v[1] = cmul(v[1], acc);
    #pragma unroll
    for (int u = 2; u < 8; u++) { acc = cmul(acc, t1); v[u] = cmul(v[u], acc); } }
  __builtin_amdgcn_wave_barrier();
  #pragma unroll
  for (int u = 0; u < 8; u++) xch[u*68 + p2*8 + u0] = v[u];
  __builtin_amdgcn_wave_barrier();
  { const float4* rp = (const float4*)(xch + u0*68 + p2*8);
    #pragma unroll
    for (int q = 0; q < 4; q++) {
      float4 t = rp[q];
      v[2*q]   = make_float2(t.x, t.y);
      v[2*q+1] = make_float2(t.z, t.w);
    } }
  dft8<S, false>(v);
  { float2 t1 = twsgn(twt[p2 << 3], S), acc = t1;
    v[1] = cmul(v[1], acc);
    #pragma unroll
    for (int u = 2; u < 8; u++) { acc = cmul(acc, t1); v[u] = cmul(v[u], acc); } }
  __builtin_amdgcn_wave_barrier();
  #pragma unroll
  for (int u = 0; u < 8; u++) xch[u*68 + lane] = v[u];
  __builtin_amdgcn_wave_barrier();
  { const float4* rp = (const float4*)(xch + p2*68 + u0*8);
    #pragma unroll
    for (int q = 0; q < 4; q++) {
      float4 t = rp[q];
      v[2*q]   = make_float2(t.x, t.y);
      v[2*q+1] = make_float2(t.z, t.w);
    } }
  dft8<S, false>(v);
}

// --- A: weights, compaction, scale, twiddle + FM tables --------------------
__global__ void __launch_bounds__(256) k_setup(const float* prm, const float* sfx,
                                               const float* sfy, char* ws) {
  __shared__ float sw[169], sx[169], sy[169];
  __shared__ double so[169];
  int t = threadIdx.x;
  if (t < 169) {
    float p = prm[t];
    float val = 1.f / (1.f + __expf(-8.f * p));
    float w = (val >= 0.001f) ? val : 0.f;
    double o = 0.0; float fx = 0.f, fy = 0.f;
    if (w > 0.f) {
      fx = sfx[t]; fy = sfy[t];
      double f2 = (double)fx*(double)fx + (double)fy*(double)fy;
      o = (double)w * sqrt((1.0 - 0.11390625 * f2) / (1.0 - 0.87890625 * f2));
    }
    sw[t] = w; so[t] = o; sx[t] = fx; sy[t] = fy;
  }
  float2* gtw = (float2*)(ws + O_TW);
  for (int k = t; k < 512; k += 256) {
    double a = 6.283185307179586476925286766559 * (double)k / 512.0;
    gtw[k] = make_float2((float)cos(a), (float)sin(a));
  }
  if (t < 241) ((float*)ws)[768 + t] = (float)(((double)(t - 120)) / 100.0);
  __syncthreads();
  if (t == 0) {
    float* wsf = (float*)ws; int* wsi = (int*)ws;
    double Sden = 0.0; int c = 0;
    for (int s = 0; s < 169; s++) {
      Sden += so[s];
      if (sw[s] > 0.f) { wsf[64+c] = sw[s]; wsf[320+c] = sx[s]; wsf[576+c] = sy[s]; c++; }
    }
    wsi[0] = c;
    // final scale; T2 carries sqrt(w)/512 per source -> refold 512^2, drop w:
    wsf[1] = (float)(1.0 / (262144.0 * 1.44 * Sden));
  }
}

// --- B1: row FFT of mask, keep window cols ---------------------------------
__global__ void __launch_bounds__(256, 6) k_b1(const float* mask, const char* wsb,
                                               float2* R1t) {
  int lane = threadIdx.x & 63, wv = threadIdx.x >> 6;
  int y = blockIdx.x * 4 + wv;
  __shared__ __align__(16) float2 lds[4*544];
  __shared__ __align__(16) float2 twt[512];
  ((float4*)twt)[threadIdx.x] = ((const float4*)(wsb + O_TW))[threadIdx.x];
  __syncthreads();
  float2 v[8];
  #pragma unroll
  for (int q = 0; q < 8; q++) v[q] = make_float2(mask[y*512 + 64*q + lane], 0.f);
  wfft512<-1, false>(v, lane, lds + wv*544, twt);
  #pragma unroll
  for (int u = 0; u < 8; u++) {
    int k = (lane>>3) + 8*(lane&7) + 64*u;
    int beta = (k >= 392) ? (k - 392) : ((k <= 120) ? (k + 120) : -1);
    if (beta >= 0) R1t[beta*512 + y] = v[u];
  }
}

// --- B2: col FFT, keep window rows -> W[alpha][beta] -----------------------
__global__ void __launch_bounds__(256, 6) k_b2(const float2* R1t, const char* wsb,
                                               float2* Wg) {
  int lane = threadIdx.x & 63, wv = threadIdx.x >> 6;
  int j = blockIdx.x * 4 + wv;                 // beta, grid 61 -> 0..243
  __shared__ __align__(16) float2 lds[4*544];
  __shared__ __align__(16) float2 twt[512];
  ((float4*)twt)[threadIdx.x] = ((const float4*)(wsb + O_TW))[threadIdx.x];
  __syncthreads();
  float2 v[8];
  #pragma unroll
  for (int q = 0; q < 8; q++)
    v[q] = (j < 241) ? R1t[j*512 + 64*q + lane] : make_float2(0.f, 0.f);
  wfft512<-1, false>(v, lane, lds + wv*544, twt);
  if (j < 241) {
    #pragma unroll
    for (int u = 0; u < 8; u++) {
      int k = (lane>>3) + 8*(lane&7) + 64*u;
      int alpha = (k >= 392) ? (k - 392) : ((k <= 120) ? (k + 120) : -1);
      if (alpha >= 0) Wg[alpha*241 + j] = v[u];
    }
  }
}

// --- C1: per source row IDFT of (W.*P)*sqrt(w)/512 -> T2 (half2) -----------
__global__ void __launch_bounds__(256, 7) k_c1(const float2* Wg, const char* wsb,
                                               int base, __half2* T2) {
  const int*   cnt = (const int*)wsb;
  const float* wsf = (const float*)wsb;
  const float* FMt = (const float*)(wsb + 3072);
  int sic  = blockIdx.x / 31;
  int tile = blockIdx.x % 31;                  // 8 alphas/tile, 2 phases of 4
  int slot = base + sic;
  if (slot >= *cnt) return;
  __shared__ __align__(16) float2 lds[4*544];  // per-wave xch, reused as tout
  __shared__ __align__(16) float2 twt[512];
  ((float4*)twt)[threadIdx.x] = ((const float4*)(wsb + O_TW))[threadIdx.x];
  __syncthreads();
  float fx = wsf[320 + slot], fy = wsf[576 + slot];
  float sqw = __fsqrt_rn(wsf[64 + slot]) * 0.001953125f;  // sqrt(w)/512
  int lane = threadIdx.x & 63, wv = threadIdx.x >> 6;
  float2* xch = lds + wv*544;
  #pragma unroll
  for (int ph = 0; ph < 2; ph++) {
    int alpha = tile*8 + ph*4 + wv;
    bool arow = (alpha < 241);
    float Gf = __fadd_rn(arow ? FMt[alpha] : 0.f, fy);
    float g2 = __fmul_rn(Gf, Gf);
    // row all-zero iff fl(G^2) > 1: r2 = fl(F^2+G^2) >= fl(G^2) (monotone)
    bool active = arow && (g2 <= 1.0f);
    float2 v[8];
    #pragma unroll
    for (int q = 0; q < 8; q++) v[q] = make_float2(0.f, 0.f);
    if (active) {
      #pragma unroll
      for (int q = 0; q < 8; q++) {
        int n = 64*q + lane;
        if (n < 241) {
          float Ff = __fadd_rn(FMt[n], fx);
          float r2 = __fadd_rn(__fmul_rn(Ff, Ff), g2); // np f32 semantics
          if (r2 <= 1.0f) {
            float num = fmaf(-0.11390625f, r2, 1.0f);
            float den = fmaf(-0.87890625f, r2, 1.0f);
            float P = __fsqrt_rn(__fsqrt_rn(__fdividef(num, den))) * sqw;
            float2 Wv = Wg[alpha*241 + n];
            v[q] = make_float2(P * Wv.x, P * Wv.y);
          }
        }
      }
      wfft512<1, false>(v, lane, xch, twt);
    }
    #pragma unroll
    for (int u = 0; u < 8; u++) {
      int xx = (lane>>3) + 8*(lane&7) + 64*u;
      xch[xx] = v[u];                           // zeros when inactive
    }
    __syncthreads();
    int colb = tile*8 + ph*4;
    if (colb < 244) {                          // tile30/ph1 would spill: skip
      #pragma unroll
      for (int r = 0; r < 2; r++) {
        int x = (int)threadIdx.x + 256*r;
        union { __half2 h[4]; float4 f; } u;
        #pragma unroll
        for (int wvi = 0; wvi < 4; wvi++) {
          float2 a = lds[wvi*544 + x];
          u.h[wvi] = __floats2half2_rn(a.x, a.y);
        }
        *(float4*)(T2 + ((size_t)sic*512 + x)*244 + colb) = u.f;
      }
    }
    __syncthreads();
  }
}

// --- C2: per source col IDFT, acc += |AA'|^2 -------------------------------
__global__ void __launch_bounds__(256, 7) k_c2(const __half2* T2, const char* wsb,
                                               int base, int CH, int first,
                                               float* accbuf) {
  const int* cnt = (const int*)wsb;
  int part = blockIdx.x & (SPLIT-1);
  int xg   = blockIdx.x >> 3;                  // 0..127
  int lane = threadIdx.x & 63, wv = threadIdx.x >> 6;
  int x = xg*4 + wv;
  __shared__ __align__(16) float2 lds[4*544];
  __shared__ __align__(16) float2 twt[512];
  ((float4*)twt)[threadIdx.x] = ((const float4*)(wsb + O_TW))[threadIdx.x];
  __syncthreads();
  float2* xch = lds + wv*544;
  int count = *cnt;
  float av[8] = {0.f,0.f,0.f,0.f,0.f,0.f,0.f,0.f};
  int sic = part;
  bool act = (sic < CH) && (base + sic < count);
  __half2 pv[4] = {{0.f,0.f},{0.f,0.f},{0.f,0.f},{0.f,0.f}};
  if (act) {
    const __half2* row = T2 + ((size_t)sic*512 + x)*244;
    #pragma unroll
    for (int q = 0; q < 4; q++) {
      int n = 64*q + lane;
      pv[q] = (n < 241) ? row[n] : __half2{0.f, 0.f};
    }
  }
  while (act) {
    float2 v[8];
    #pragma unroll
    for (int q = 0; q < 4; q++) { float2 f = __half22float2(pv[q]); v[q] = f; }
    #pragma unroll
    for (int q = 4; q < 8; q++) v[q] = make_float2(0.f, 0.f);
    int nsic = sic + SPLIT;
    act = (nsic < CH) && (base + nsic < count);
    if (act) {                                  // prefetch across the FFT
      const __half2* row = T2 + ((size_t)nsic*512 + x)*244;
      #pragma unroll
      for (int q = 0; q < 4; q++) {
        int n = 64*q + lane;
        pv[q] = (n < 241) ? row[n] : __half2{0.f, 0.f};
      }
    }
    wfft512<1, true>(v, lane, xch, twt);
    #pragma unroll
    for (int u = 0; u < 8; u++)
      av[u] += fmaf(v[u].x, v[u].x, v[u].y*v[u].y);
    sic = nsic;
  }
  float* a = accbuf + ((size_t)part << 18) + (size_t)x * 512;
  int y0 = (lane>>3) + 8*(lane&7);
  if (first) {
    #pragma unroll
    for (int u = 0; u < 8; u++) a[y0 + 64*u] = av[u];
  } else {
    #pragma unroll
    for (int u = 0; u < 8; u++) a[y0 + 64*u] += av[u];
  }
}

// --- D: transpose-tile, scale, doses, resist sigmoid -----------------------
__global__ void __launch_bounds__(256) k_final(const float* acc, const char* wsb,
                                               float* out) {
  __shared__ float tile[64][65];
  const float* wsf = (const float*)wsb;
  float scale = wsf[1];
  int x0 = (blockIdx.x & 7) * 64, y0 = (blockIdx.x >> 3) * 64;
  int j = threadIdx.x & 63, i0 = threadIdx.x >> 6;
  #pragma unroll
  for (int k = 0; k < 16; k++) {
    int i = i0 + 4*k;
    const float* ap = acc + (size_t)(x0 + i)*512 + y0 + j;
    float s = 0.f;
    #pragma unroll
    for (int p = 0; p < SPLIT; p++) s += ap[(size_t)p << 18];
    tile[i][j] = s;
  }
  __syncthreads();
  const float dd[3] = {0.9604f, 1.0f, 1.0404f};
  #pragma unroll
  for (int k = 0; k < 16; k++) {
    int yy = i0 + 4*k;
    float I = scale * tile[j][yy];
    int o = (y0 + yy)*512 + x0 + j;
    #pragma unroll
    for (int d = 0; d < 3; d++) {
      float Ik = dd[d] * I;
      out[(size_t)d*262144 + o] = Ik;
      out[(size_t)(3+d)*262144 + o] = 1.f / (1.f + __expf(-30.f*(Ik - 0.225f)));
    }
  }
}

extern "C" void kernel_launch(void* const* d_in, const int* in_sizes, int n_in,
                              void* d_out, int out_size, void* d_ws, size_t ws_size,
                              hipStream_t stream) {
  (void)in_sizes; (void)n_in; (void)out_size;
  const float* mask = (const float*)d_in[0];
  const float* prm  = (const float*)d_in[1];
  const float* sfx  = (const float*)d_in[2];
  const float* sfy  = (const float*)d_in[3];
  float* out = (float*)d_out;
  char*  ws  = (char*)d_ws;

  float*   acc = (float*)(ws + O_ACC);
  float2*  Wg  = (float2*)(ws + O_WIN);
  float2*  R1t = (float2*)(ws + O_R1);
  __half2* T2  = (__half2*)(ws + O_T2);

  k_setup<<<dim3(1),   dim3(256), 0, stream>>>(prm, sfx, sfy, ws);
  k_b1  <<<dim3(128), dim3(256), 0, stream>>>(mask, (const char*)ws, R1t);
  k_b2  <<<dim3(61),  dim3(256), 0, stream>>>(R1t, (const char*)ws, Wg);

  size_t avail = (ws_size > O_T2) ? (ws_size - O_T2) : 0;
  int CH = (int)(avail / SLOT_BYTES);
  if (CH > 169) CH = 169;
  if (CH < 1)   CH = 1;
  for (int base = 0; base < 169; base += CH) {
    k_c1<<<dim3((unsigned)(CH*31)),  dim3(256), 0, stream>>>(Wg, (const char*)ws, base, T2);
    k_c2<<<dim3(128*SPLIT),          dim3(256), 0, stream>>>(T2, (const char*)ws, base, CH,
                                                             (base == 0) ? 1 : 0, acc);
  }
  k_final<<<dim3(64), dim3(256), 0, stream>>>(acc, (const char*)ws, out);
}

// Round 6
// 138.332 us; speedup vs baseline: 1.2276x; 1.0283x over previous
//
#include <hip/hip_runtime.h>
#include <hip/hip_bf16.h>
#include <hip/hip_fp16.h>

// ---------------------------------------------------------------------------
// Abbe lithography forward. Doses factor out (I(d)=d^2 I(1)); all shift
// phases cancel in |AA|^2; weight cancels against norm_I. Source-pair
// symmetry: for s'=(-fx,-fy), |AA_s'|^2 == |AA_s|^2 exactly (W Hermitian
// about window center + FM grid odd-symmetric in f32), so +/- pairs are
// merged in k_setup with combined weight (~60 -> ~30 sources).
//   A : weights+pair-merge+compaction, scale, twiddle table, FM grid
//   B1: row FFT of mask, keep 241 window cols  -> R1t[beta][y]
//   B2: col FFT, keep 241 window rows          -> W[alpha][beta]
//   C1: per source row IDFT of (W.*P)*sqrt(w)/512 -> T2[s][x][alpha] (fp16)
//       rows with fl(G^2)>1 provably all-zero -> skip FFT, store zeros.
//   C2: per source col IDFT, acc += |AA'|^2    -> acc[part][x][y]
//   D : scale (x512^2 refold), 3 doses, resist sigmoid (LDS transpose)
// FFT-512: radix-8, 3 stages, one wave per FFT, wave-level sync only.
// Exchange layouts: writes 2-way (free), reads contiguous ds_read_b128.
// Output reg u of lane L holds X[(L>>3) + 8*(L&7) + 64*u].
// ---------------------------------------------------------------------------

#define SPLIT 8

static const size_t O_TW   = 4096;                       // float2[512]
static const size_t O_ACC  = 8192;                       // SPLIT*512*512*f32
static const size_t ACC_BYTES = (size_t)SPLIT * 512 * 512 * 4;
static const size_t O_WIN  = O_ACC + ACC_BYTES;
static const size_t O_R1   = O_WIN + 464896;
static const size_t O_T2   = O_R1 + 987136;
static const size_t SLOT_BYTES = (size_t)512 * 244 * 4;  // half2 slots

__device__ inline float2 cadd(float2 a, float2 b){ return make_float2(a.x+b.x, a.y+b.y); }
__device__ inline float2 csub(float2 a, float2 b){ return make_float2(a.x-b.x, a.y-b.y); }
__device__ inline float2 cmul(float2 a, float2 b){
  return make_float2(fmaf(a.x, b.x, -(a.y*b.y)), fmaf(a.x, b.y, a.y*b.x));
}
__device__ inline float2 twsgn(float2 t, int S) {
  return make_float2(t.x, (S > 0) ? t.y : -t.y);
}

// Radix-8 butterfly. If ZTOP, v[4..7] are known zero (skips first add level).
template<int S, bool ZTOP>
__device__ inline void dft8(float2 v[8]) {
  const float sg = (float)S;
  const float C7 = 0.7071067811865476f;
  float2 t0, t1, t2, t3, t4, t5, t6, t7;
  if (ZTOP) {
    t0 = v[0]; t4 = v[0];
    t1 = v[1]; t5 = v[1];
    t2 = v[2]; t6 = v[2];
    t3 = v[3]; t7 = v[3];
  } else {
    t0=cadd(v[0],v[4]); t4=csub(v[0],v[4]);
    t1=cadd(v[1],v[5]); t5=csub(v[1],v[5]);
    t2=cadd(v[2],v[6]); t6=csub(v[2],v[6]);
    t3=cadd(v[3],v[7]); t7=csub(v[3],v[7]);
  }
  t5 = make_float2(C7*(t5.x - sg*t5.y), C7*(t5.y + sg*t5.x));
  t6 = make_float2(-sg*t6.y, sg*t6.x);
  t7 = make_float2(C7*(-t7.x - sg*t7.y), C7*(sg*t7.x - t7.y));
  float2 u0=cadd(t0,t2), u2=csub(t0,t2);
  float2 u1=cadd(t1,t3), u3=csub(t1,t3);
  u3 = make_float2(-sg*u3.y, sg*u3.x);
  float2 u4=cadd(t4,t6), u6=csub(t4,t6);
  float2 u5=cadd(t5,t7), u7=csub(t5,t7);
  u7 = make_float2(-sg*u7.y, sg*u7.x);
  v[0]=cadd(u0,u1); v[4]=csub(u0,u1);
  v[2]=cadd(u2,u3); v[6]=csub(u2,u3);
  v[1]=cadd(u4,u5); v[5]=csub(u4,u5);
  v[3]=cadd(u6,u7); v[7]=csub(u6,u7);
}

// One-wave FFT-512; xch = per-wave float2[544] (16B aligned). Wave-sync only.
template<int S, bool ZTOP>
__device__ inline void wfft512(float2 v[8], int lane, float2* xch,
                               const float2* twt) {
  const int p2 = lane & 7, u0 = lane >> 3;
  dft8<S, ZTOP>(v);
  { float2 t1 = twsgn(twt[lane], S), acc = t1;
    v[1] = cmul(v[1], acc);
    #pragma unroll
    for (int u = 2; u < 8; u++) { acc = cmul(acc, t1); v[u] = cmul(v[u], acc); } }
  __builtin_amdgcn_wave_barrier();
  #pragma unroll
  for (int u = 0; u < 8; u++) xch[u*68 + p2*8 + u0] = v[u];
  __builtin_amdgcn_wave_barrier();
  { const float4* rp = (const float4*)(xch + u0*68 + p2*8);
    #pragma unroll
    for (int q = 0; q < 4; q++) {
      float4 t = rp[q];
      v[2*q]   = make_float2(t.x, t.y);
      v[2*q+1] = make_float2(t.z, t.w);
    } }
  dft8<S, false>(v);
  { float2 t1 = twsgn(twt[p2 << 3], S), acc = t1;
    v[1] = cmul(v[1], acc);
    #pragma unroll
    for (int u = 2; u < 8; u++) { acc = cmul(acc, t1); v[u] = cmul(v[u], acc); } }
  __builtin_amdgcn_wave_barrier();
  #pragma unroll
  for (int u = 0; u < 8; u++) xch[u*68 + lane] = v[u];
  __builtin_amdgcn_wave_barrier();
  { const float4* rp = (const float4*)(xch + p2*68 + u0*8);
    #pragma unroll
    for (int q = 0; q < 4; q++) {
      float4 t = rp[q];
      v[2*q]   = make_float2(t.x, t.y);
      v[2*q+1] = make_float2(t.z, t.w);
    } }
  dft8<S, false>(v);
}

// --- A: weights, pair-merge, compaction, scale, twiddle + FM tables --------
__global__ void __launch_bounds__(256) k_setup(const float* prm, const float* sfx,
                                               const float* sfy, char* ws) {
  __shared__ float sw[169], sx[169], sy[169], scw[169];
  __shared__ double so[169];
  __shared__ int skeep[169];
  int t = threadIdx.x;
  if (t < 169) {
    float p = prm[t];
    float val = 1.f / (1.f + __expf(-8.f * p));
    float w = (val >= 0.001f) ? val : 0.f;
    double o = 0.0; float fx = 0.f, fy = 0.f;
    if (w > 0.f) {
      fx = sfx[t]; fy = sfy[t];
      double f2 = (double)fx*(double)fx + (double)fy*(double)fy;
      o = (double)w * sqrt((1.0 - 0.11390625 * f2) / (1.0 - 0.87890625 * f2));
    }
    sw[t] = w; so[t] = o; sx[t] = fx; sy[t] = fy;
  }
  float2* gtw = (float2*)(ws + O_TW);
  for (int k = t; k < 512; k += 256) {
    double a = 6.283185307179586476925286766559 * (double)k / 512.0;
    gtw[k] = make_float2((float)cos(a), (float)sin(a));
  }
  if (t < 241) ((float*)ws)[768 + t] = (float)(((double)(t - 120)) / 100.0);
  __syncthreads();
  // pair s with s'=(-fx,-fy): |AA_s'|^2 == |AA_s|^2 exactly, merge weights
  if (t < 169) {
    float w = sw[t];
    int keep = 0; float cw = w;
    if (w > 0.f) {
      float fx = sx[t], fy = sy[t];
      int pr = -1;
      for (int s2 = 0; s2 < 169; s2++) {
        if (sw[s2] > 0.f && fabsf(sx[s2] + fx) < 1e-5f
                         && fabsf(sy[s2] + fy) < 1e-5f) { pr = s2; break; }
      }
      if (pr < 0 || pr == t) keep = 1;                  // unpaired / self
      else if (pr > t) { keep = 1; cw = w + sw[pr]; }   // canonical member
    }
    skeep[t] = keep; scw[t] = cw;
  }
  __syncthreads();
  if (t == 0) {
    float* wsf = (float*)ws; int* wsi = (int*)ws;
    double Sden = 0.0; int c = 0;
    for (int s = 0; s < 169; s++) {
      Sden += so[s];                                    // norm over ALL valid
      if (skeep[s]) { wsf[64+c] = scw[s]; wsf[320+c] = sx[s]; wsf[576+c] = sy[s]; c++; }
    }
    wsi[0] = c;
    // final scale; T2 carries sqrt(w)/512 per source -> refold 512^2, drop w:
    wsf[1] = (float)(1.0 / (262144.0 * 1.44 * Sden));
  }
}

// --- B1: row FFT of mask, keep window cols ---------------------------------
__global__ void __launch_bounds__(256, 6) k_b1(const float* mask, const char* wsb,
                                               float2* R1t) {
  int lane = threadIdx.x & 63, wv = threadIdx.x >> 6;
  int y = blockIdx.x * 4 + wv;
  __shared__ __align__(16) float2 lds[4*544];
  __shared__ __align__(16) float2 twt[512];
  ((float4*)twt)[threadIdx.x] = ((const float4*)(wsb + O_TW))[threadIdx.x];
  __syncthreads();
  float2 v[8];
  #pragma unroll
  for (int q = 0; q < 8; q++) v[q] = make_float2(mask[y*512 + 64*q + lane], 0.f);
  wfft512<-1, false>(v, lane, lds + wv*544, twt);
  #pragma unroll
  for (int u = 0; u < 8; u++) {
    int k = (lane>>3) + 8*(lane&7) + 64*u;
    int beta = (k >= 392) ? (k - 392) : ((k <= 120) ? (k + 120) : -1);
    if (beta >= 0) R1t[beta*512 + y] = v[u];
  }
}

// --- B2: col FFT, keep window rows -> W[alpha][beta] -----------------------
__global__ void __launch_bounds__(256, 6) k_b2(const float2* R1t, const char* wsb,
                                               float2* Wg) {
  int lane = threadIdx.x & 63, wv = threadIdx.x >> 6;
  int j = blockIdx.x * 4 + wv;                 // beta, grid 61 -> 0..243
  __shared__ __align__(16) float2 lds[4*544];
  __shared__ __align__(16) float2 twt[512];
  ((float4*)twt)[threadIdx.x] = ((const float4*)(wsb + O_TW))[threadIdx.x];
  __syncthreads();
  float2 v[8];
  #pragma unroll
  for (int q = 0; q < 8; q++)
    v[q] = (j < 241) ? R1t[j*512 + 64*q + lane] : make_float2(0.f, 0.f);
  wfft512<-1, false>(v, lane, lds + wv*544, twt);
  if (j < 241) {
    #pragma unroll
    for (int u = 0; u < 8; u++) {
      int k = (lane>>3) + 8*(lane&7) + 64*u;
      int alpha = (k >= 392) ? (k - 392) : ((k <= 120) ? (k + 120) : -1);
      if (alpha >= 0) Wg[alpha*241 + j] = v[u];
    }
  }
}

// --- C1: per source row IDFT of (W.*P)*sqrt(w)/512 -> T2 (half2) -----------
__global__ void __launch_bounds__(256, 7) k_c1(const float2* Wg, const char* wsb,
                                               int base, __half2* T2) {
  const int*   cnt = (const int*)wsb;
  const float* wsf = (const float*)wsb;
  const float* FMt = (const float*)(wsb + 3072);
  int sic  = blockIdx.x / 31;
  int tile = blockIdx.x % 31;                  // 8 alphas/tile, 2 phases of 4
  int slot = base + sic;
  if (slot >= *cnt) return;
  __shared__ __align__(16) float2 lds[4*544];  // per-wave xch, reused as tout
  __shared__ __align__(16) float2 twt[512];
  ((float4*)twt)[threadIdx.x] = ((const float4*)(wsb + O_TW))[threadIdx.x];
  __syncthreads();
  float fx = wsf[320 + slot], fy = wsf[576 + slot];
  float sqw = __fsqrt_rn(wsf[64 + slot]) * 0.001953125f;  // sqrt(w)/512
  int lane = threadIdx.x & 63, wv = threadIdx.x >> 6;
  float2* xch = lds + wv*544;
  #pragma unroll
  for (int ph = 0; ph < 2; ph++) {
    int alpha = tile*8 + ph*4 + wv;
    bool arow = (alpha < 241);
    float Gf = __fadd_rn(arow ? FMt[alpha] : 0.f, fy);
    float g2 = __fmul_rn(Gf, Gf);
    // row all-zero iff fl(G^2) > 1: r2 = fl(F^2+G^2) >= fl(G^2) (monotone)
    bool active = arow && (g2 <= 1.0f);
    float2 v[8];
    #pragma unroll
    for (int q = 0; q < 8; q++) v[q] = make_float2(0.f, 0.f);
    if (active) {
      #pragma unroll
      for (int q = 0; q < 4; q++) {              // n<241 -> q<4 only
        int n = 64*q + lane;
        if (n < 241) {
          float Ff = __fadd_rn(FMt[n], fx);
          float r2 = __fadd_rn(__fmul_rn(Ff, Ff), g2); // np f32 semantics
          if (r2 <= 1.0f) {
            float num = fmaf(-0.11390625f, r2, 1.0f);
            float den = fmaf(-0.87890625f, r2, 1.0f);
            float P = __fsqrt_rn(__fsqrt_rn(__fdividef(num, den))) * sqw;
            float2 Wv = Wg[alpha*241 + n];
            v[q] = make_float2(P * Wv.x, P * Wv.y);
          }
        }
      }
      wfft512<1, true>(v, lane, xch, twt);
    }
    #pragma unroll
    for (int u = 0; u < 8; u++) {
      int xx = (lane>>3) + 8*(lane&7) + 64*u;
      xch[xx] = v[u];                           // zeros when inactive
    }
    __syncthreads();
    int colb = tile*8 + ph*4;
    if (colb < 244) {                          // tile30/ph1 would spill: skip
      #pragma unroll
      for (int r = 0; r < 2; r++) {
        int x = (int)threadIdx.x + 256*r;
        union { __half2 h[4]; float4 f; } u;
        #pragma unroll
        for (int wvi = 0; wvi < 4; wvi++) {
          float2 a = lds[wvi*544 + x];
          u.h[wvi] = __floats2half2_rn(a.x, a.y);
        }
        *(float4*)(T2 + ((size_t)sic*512 + x)*244 + colb) = u.f;
      }
    }
    __syncthreads();
  }
}

// --- C2: per source col IDFT, acc += |AA'|^2 -------------------------------
__global__ void __launch_bounds__(256, 7) k_c2(const __half2* T2, const char* wsb,
                                               int base, int CH, int first,
                                               float* accbuf) {
  const int* cnt = (const int*)wsb;
  int part = blockIdx.x & (SPLIT-1);
  int xg   = blockIdx.x >> 3;                  // 0..127
  int lane = threadIdx.x & 63, wv = threadIdx.x >> 6;
  int x = xg*4 + wv;
  __shared__ __align__(16) float2 lds[4*544];
  __shared__ __align__(16) float2 twt[512];
  ((float4*)twt)[threadIdx.x] = ((const float4*)(wsb + O_TW))[threadIdx.x];
  __syncthreads();
  float2* xch = lds + wv*544;
  int count = *cnt;
  float av[8] = {0.f,0.f,0.f,0.f,0.f,0.f,0.f,0.f};
  int sic = part;
  bool act = (sic < CH) && (base + sic < count);
  __half2 pv[4] = {{0.f,0.f},{0.f,0.f},{0.f,0.f},{0.f,0.f}};
  if (act) {
    const __half2* row = T2 + ((size_t)sic*512 + x)*244;
    #pragma unroll
    for (int q = 0; q < 4; q++) {
      int n = 64*q + lane;
      pv[q] = (n < 241) ? row[n] : __half2{0.f, 0.f};
    }
  }
  while (act) {
    float2 v[8];
    #pragma unroll
    for (int q = 0; q < 4; q++) { float2 f = __half22float2(pv[q]); v[q] = f; }
    #pragma unroll
    for (int q = 4; q < 8; q++) v[q] = make_float2(0.f, 0.f);
    int nsic = sic + SPLIT;
    act = (nsic < CH) && (base + nsic < count);
    if (act) {                                  // prefetch across the FFT
      const __half2* row = T2 + ((size_t)nsic*512 + x)*244;
      #pragma unroll
      for (int q = 0; q < 4; q++) {
        int n = 64*q + lane;
        pv[q] = (n < 241) ? row[n] : __half2{0.f, 0.f};
      }
    }
    wfft512<1, true>(v, lane, xch, twt);
    #pragma unroll
    for (int u = 0; u < 8; u++)
      av[u] += fmaf(v[u].x, v[u].x, v[u].y*v[u].y);
    sic = nsic;
  }
  float* a = accbuf + ((size_t)part << 18) + (size_t)x * 512;
  int y0 = (lane>>3) + 8*(lane&7);
  if (first) {
    #pragma unroll
    for (int u = 0; u < 8; u++) a[y0 + 64*u] = av[u];
  } else {
    #pragma unroll
    for (int u = 0; u < 8; u++) a[y0 + 64*u] += av[u];
  }
}

// --- D: transpose-tile, scale, doses, resist sigmoid -----------------------
__global__ void __launch_bounds__(256) k_final(const float* acc, const char* wsb,
                                               float* out) {
  __shared__ float tile[64][65];
  const float* wsf = (const float*)wsb;
  float scale = wsf[1];
  int x0 = (blockIdx.x & 7) * 64, y0 = (blockIdx.x >> 3) * 64;
  int j = threadIdx.x & 63, i0 = threadIdx.x >> 6;
  #pragma unroll
  for (int k = 0; k < 16; k++) {
    int i = i0 + 4*k;
    const float* ap = acc + (size_t)(x0 + i)*512 + y0 + j;
    float s = 0.f;
    #pragma unroll
    for (int p = 0; p < SPLIT; p++) s += ap[(size_t)p << 18];
    tile[i][j] = s;
  }
  __syncthreads();
  const float dd[3] = {0.9604f, 1.0f, 1.0404f};
  #pragma unroll
  for (int k = 0; k < 16; k++) {
    int yy = i0 + 4*k;
    float I = scale * tile[j][yy];
    int o = (y0 + yy)*512 + x0 + j;
    #pragma unroll
    for (int d = 0; d < 3; d++) {
      float Ik = dd[d] * I;
      out[(size_t)d*262144 + o] = Ik;
      out[(size_t)(3+d)*262144 + o] = 1.f / (1.f + __expf(-30.f*(Ik - 0.225f)));
    }
  }
}

extern "C" void kernel_launch(void* const* d_in, const int* in_sizes, int n_in,
                              void* d_out, int out_size, void* d_ws, size_t ws_size,
                              hipStream_t stream) {
  (void)in_sizes; (void)n_in; (void)out_size;
  const float* mask = (const float*)d_in[0];
  const float* prm  = (const float*)d_in[1];
  const float* sfx  = (const float*)d_in[2];
  const float* sfy  = (const float*)d_in[3];
  float* out = (float*)d_out;
  char*  ws  = (char*)d_ws;

  float*   acc = (float*)(ws + O_ACC);
  float2*  Wg  = (float2*)(ws + O_WIN);
  float2*  R1t = (float2*)(ws + O_R1);
  __half2* T2  = (__half2*)(ws + O_T2);

  k_setup<<<dim3(1),   dim3(256), 0, stream>>>(prm, sfx, sfy, ws);
  k_b1  <<<dim3(128), dim3(256), 0, stream>>>(mask, (const char*)ws, R1t);
  k_b2  <<<dim3(61),  dim3(256), 0, stream>>>(R1t, (const char*)ws, Wg);

  size_t avail = (ws_size > O_T2) ? (ws_size - O_T2) : 0;
  int CH = (int)(avail / SLOT_BYTES);
  if (CH > 169) CH = 169;
  if (CH < 1)   CH = 1;
  for (int base = 0; base < 169; base += CH) {
    k_c1<<<dim3((unsigned)(CH*31)),  dim3(256), 0, stream>>>(Wg, (const char*)ws, base, T2);
    k_c2<<<dim3(128*SPLIT),          dim3(256), 0, stream>>>(T2, (const char*)ws, base, CH,
                                                             (base == 0) ? 1 : 0, acc);
  }
  k_final<<<dim3(64), dim3(256), 0, stream>>>(acc, (const char*)ws, out);
}